// Round 5
// baseline (784.570 us; speedup 1.0000x reference)
//
#include <hip/hip_runtime.h>
#include <hip/hip_bf16.h>
#include <math.h>

#define NB 32
#define LSEQ 2048
#define DIN 64
#define NH 256
#define NN 32
#define NLAY 2
#define NCH 32
#define TCH 64    // LSEQ/NCH
#define LTILE 64
#define ML1 350
#define ML2 400
#define MOUT 1024
#define LN_EPS 1e-5f

typedef short short8 __attribute__((ext_vector_type(8)));
typedef float f32x4 __attribute__((ext_vector_type(4)));

// ---------------- coefficient prep ----------------
__global__ void s4w_coef(const float* __restrict__ log_dt,
                         const float* __restrict__ C_re, const float* __restrict__ C_im,
                         const float* __restrict__ log_A_real, const float* __restrict__ A_imag,
                         float* __restrict__ ctr, float* __restrict__ cti,
                         float* __restrict__ er_, float* __restrict__ ei_,
                         float* __restrict__ pr_, float* __restrict__ pi_) {
    int idx = blockIdx.x * 256 + threadIdx.x;
    if (idx >= NLAY * NH * NN) return;
    int h = (idx / NN) % NH;
    int l = idx / (NN * NH);
    float dt = expf(log_dt[l * NH + h]);
    float ar = -expf(log_A_real[idx]);
    float ai = A_imag[idx];
    float dre = ar * dt, dim = ai * dt;
    float ex = expf(dre);
    float er = ex * cosf(dim);
    float ei = ex * sinf(dim);
    float den = ar * ar + ai * ai;
    float qr = ((er - 1.0f) * ar + ei * ai) / den;
    float qi = (ei * ar - (er - 1.0f) * ai) / den;
    float cr = C_re[idx], ci = C_im[idx];
    ctr[idx] = 2.0f * (cr * qr - ci * qi);
    cti[idx] = 2.0f * (cr * qi + ci * qr);
    er_[idx] = er; ei_[idx] = ei;
    double exT = exp((double)dre * (double)TCH);
    double ang = (double)dim * (double)TCH;
    pr_[idx] = (float)(exT * cos(ang));
    pi_[idx] = (float)(exT * sin(ang));
}

// ---------------- weight prep: out_w -> bf16 (both layers) ----------------
__global__ void s4w_wprep(const float* __restrict__ ow, __hip_bfloat16* __restrict__ wbf) {
    int idx = blockIdx.x * 256 + threadIdx.x;
    wbf[idx] = __float2bfloat16(ow[idx]);
}

// ---------------- encoder: block = (b, 16 l's), thread = o; coalesced writes ----------------
__global__ void __launch_bounds__(256, 2)
s4w_enc(const float* __restrict__ x, const float* __restrict__ w,
        const float* __restrict__ bias, float* __restrict__ hbuf) {
    int blk = blockIdx.x;
    int b = blk / (LSEQ / 16);
    int l0 = (blk % (LSEQ / 16)) * 16;
    int t = threadIdx.x;
    __shared__ float xs[16][DIN];    // 4 KB
    ((float4*)&xs[0][0])[t] = ((const float4*)(x + ((size_t)b * LSEQ + l0) * DIN))[t];
    float wr[DIN];
    const float4* wp4 = (const float4*)(w + (size_t)t * DIN);
#pragma unroll
    for (int i = 0; i < DIN / 4; i++) {
        float4 v = wp4[i];
        wr[4 * i] = v.x; wr[4 * i + 1] = v.y; wr[4 * i + 2] = v.z; wr[4 * i + 3] = v.w;
    }
    float bz = bias[t];
    __syncthreads();
#pragma unroll 4
    for (int l = 0; l < 16; l++) {
        float acc = bz;
#pragma unroll
        for (int i = 0; i < DIN; i++) acc = fmaf(wr[i], xs[l][i], acc);
        hbuf[((size_t)b * LSEQ + l0 + l) * NH + t] = acc;
    }
}

// ---------------- conv phase A: per-chunk local end states ----------------
__global__ void __launch_bounds__(256, 1)
s4w_convA(const float* __restrict__ hbuf,
          const float* __restrict__ er_, const float* __restrict__ ei_,
          float2* __restrict__ states, int layer) {
    int b = blockIdx.x, c = blockIdx.y, h = threadIdx.x;
    float er[NN], ei[NN], sr[NN], si[NN];
    const float* eb0 = er_ + (size_t)(layer * NH + h) * NN;
    const float* eb1 = ei_ + (size_t)(layer * NH + h) * NN;
#pragma unroll
    for (int n = 0; n < NN; n++) { er[n] = eb0[n]; ei[n] = eb1[n]; sr[n] = 0.f; si[n] = 0.f; }
    const float* up = hbuf + ((size_t)b * LSEQ + c * TCH) * NH + h;
#pragma unroll 4
    for (int j = 0; j < TCH; j++) {
        float u = up[(size_t)j * NH];
#pragma unroll
        for (int n = 0; n < NN; n++) {
            float nsr = fmaf(er[n], sr[n], fmaf(-ei[n], si[n], u));
            float nsi = fmaf(er[n], si[n], ei[n] * sr[n]);
            sr[n] = nsr; si[n] = nsi;
        }
    }
    float2* sp = states + ((size_t)(b * NCH + c) * NH + h) * NN;
#pragma unroll
    for (int n = 0; n < NN; n++) sp[n] = make_float2(sr[n], si[n]);
}

// ---------------- conv phase B: inter-chunk scan ----------------
__global__ void s4w_scan(float2* __restrict__ states,
                         const float* __restrict__ pr_, const float* __restrict__ pi_, int layer) {
    int idx = blockIdx.x * 256 + threadIdx.x;
    int b = idx / (NH * NN);
    int hn = idx % (NH * NN);
    float pr = pr_[(size_t)layer * NH * NN + hn];
    float pi = pi_[(size_t)layer * NH * NN + hn];
    float sr = 0.f, si = 0.f;
    float2* sp = states + (size_t)b * NCH * NH * NN + hn;
    for (int c = 0; c < NCH; c++) {
        float2 e = sp[(size_t)c * NH * NN];
        sp[(size_t)c * NH * NN] = make_float2(sr, si);
        float nsr = pr * sr - pi * si + e.x;
        float nsi = pr * si + pi * sr + e.y;
        sr = nsr; si = nsi;
    }
}

// ---------------- conv phase C: replay + Dp skip + GELU -> bf16 ----------------
__global__ void __launch_bounds__(256, 1)
s4w_convC(const float* __restrict__ hbuf, __hip_bfloat16* __restrict__ ybf,
          const float2* __restrict__ states,
          const float* __restrict__ er_, const float* __restrict__ ei_,
          const float* __restrict__ ctr_, const float* __restrict__ cti_,
          const float* __restrict__ Dp, int layer) {
    int b = blockIdx.x, c = blockIdx.y, h = threadIdx.x;
    float er[NN], ei[NN], sr[NN], si[NN], cr[NN], ci[NN];
    size_t cbase = (size_t)(layer * NH + h) * NN;
    const float2* sp = states + ((size_t)(b * NCH + c) * NH + h) * NN;
#pragma unroll
    for (int n = 0; n < NN; n++) {
        er[n] = er_[cbase + n]; ei[n] = ei_[cbase + n];
        cr[n] = ctr_[cbase + n]; ci[n] = cti_[cbase + n];
        float2 s0 = sp[n];
        sr[n] = s0.x; si[n] = s0.y;
    }
    float dp = Dp[layer * NH + h];
    const float* up = hbuf + ((size_t)b * LSEQ + c * TCH) * NH + h;
    __hip_bfloat16* yp = ybf + ((size_t)b * LSEQ + c * TCH) * NH + h;
#pragma unroll 2
    for (int j = 0; j < TCH; j++) {
        float u = up[(size_t)j * NH];
        float a0 = 0.f, a1 = 0.f;
#pragma unroll
        for (int n = 0; n < NN; n++) {
            float nsr = fmaf(er[n], sr[n], fmaf(-ei[n], si[n], u));
            float nsi = fmaf(er[n], si[n], ei[n] * sr[n]);
            sr[n] = nsr; si[n] = nsi;
            if (n & 1) { a1 = fmaf(cr[n], nsr, a1); a1 = fmaf(-ci[n], nsi, a1); }
            else       { a0 = fmaf(cr[n], nsr, a0); a0 = fmaf(-ci[n], nsi, a0); }
        }
        float yv = a0 + a1;
        yv = fmaf(u, dp, yv);
        float g = 0.5f * yv * (1.0f + erff(yv * 0.70710678118f));
        yp[(size_t)j * NH] = __float2bfloat16(g);
    }
}

// ---------------- proj: bf16 MFMA GEMM + GLU + residual + channel-LN ----------------
__global__ void __launch_bounds__(256, 2)
s4w_proj_mfma(const __hip_bfloat16* __restrict__ ybf, float* __restrict__ hbuf,
              const __hip_bfloat16* __restrict__ wbf, const float* __restrict__ ob,
              const float* __restrict__ lnw, const float* __restrict__ lnb, int layer) {
    int b = blockIdx.x;
    int n0 = blockIdx.y * LTILE;
    int t = threadIdx.x;
    int wave = t >> 6, lane = t & 63;
    int lm = lane & 15, kg = lane >> 4;

    __shared__ float glu[LTILE][NH + 1];
    __shared__ float ps[256], pq[256];
    __shared__ float mean_s[LTILE], rstd_s[LTILE];

    f32x4 acc[8][4];
#pragma unroll
    for (int i = 0; i < 8; i++)
#pragma unroll
        for (int j = 0; j < 4; j++) acc[i][j] = (f32x4){0.f, 0.f, 0.f, 0.f};

    const short* wp = (const short*)(wbf) + (size_t)layer * 512 * NH;
    const short* yp = (const short*)(ybf) + ((size_t)b * LSEQ + n0) * NH;

    const short8* aptr[8];
#pragma unroll
    for (int mi = 0; mi < 8; mi++) {
        int o = (mi < 4 ? wave * 64 + mi * 16 : 256 + wave * 64 + (mi - 4) * 16) + lm;
        aptr[mi] = (const short8*)(wp + (size_t)o * NH + kg * 8);
    }
    const short8* bptr[4];
#pragma unroll
    for (int ni = 0; ni < 4; ni++) {
        int l = ni * 16 + lm;
        bptr[ni] = (const short8*)(yp + (size_t)l * NH + kg * 8);
    }

#pragma unroll
    for (int ks = 0; ks < 8; ks++) {
        short8 bv[4], av[8];
#pragma unroll
        for (int ni = 0; ni < 4; ni++) bv[ni] = bptr[ni][ks * 4];
#pragma unroll
        for (int mi = 0; mi < 8; mi++) av[mi] = aptr[mi][ks * 4];
#pragma unroll
        for (int mi = 0; mi < 8; mi++)
#pragma unroll
            for (int ni = 0; ni < 4; ni++)
                acc[mi][ni] = __builtin_amdgcn_mfma_f32_16x16x32_bf16(av[mi], bv[ni], acc[mi][ni], 0, 0, 0);
    }

    float oba[4][4], obg[4][4];
#pragma unroll
    for (int mi = 0; mi < 4; mi++)
#pragma unroll
        for (int j = 0; j < 4; j++) {
            int o = wave * 64 + mi * 16 + kg * 4 + j;
            oba[mi][j] = ob[layer * 2 * NH + o];
            obg[mi][j] = ob[layer * 2 * NH + NH + o];
        }
#pragma unroll
    for (int mi = 0; mi < 4; mi++)
#pragma unroll
        for (int ni = 0; ni < 4; ni++)
#pragma unroll
            for (int j = 0; j < 4; j++) {
                float a = acc[mi][ni][j] + oba[mi][j];
                float g = acc[mi + 4][ni][j] + obg[mi][j];
                float v = a * (1.0f / (1.0f + expf(-g)));
                int o = wave * 64 + mi * 16 + kg * 4 + j;
                int l = ni * 16 + lm;
                glu[l][o] = v;
            }
    __syncthreads();

    const size_t hbase = ((size_t)b * LSEQ + n0) * NH;
    for (int l = 0; l < LTILE; l++)
        glu[l][t] += hbuf[hbase + (size_t)l * NH + t];
    __syncthreads();

    {
        int l = t & 63, seg = t >> 6;
        float s = 0.f, q = 0.f;
#pragma unroll
        for (int i = 0; i < 64; i++) {
            float v = glu[l][seg * 64 + i];
            s += v; q = fmaf(v, v, q);
        }
        ps[t] = s; pq[t] = q;
    }
    __syncthreads();
    if (t < 64) {
        float S = ps[t] + ps[64 + t] + ps[128 + t] + ps[192 + t];
        float Q = pq[t] + pq[64 + t] + pq[128 + t] + pq[192 + t];
        float m = S * (1.0f / NH);
        float v = Q * (1.0f / NH) - m * m;
        mean_s[t] = m; rstd_s[t] = rsqrtf(v + LN_EPS);
    }
    __syncthreads();

    float lw = lnw[layer * NH + t], lb = lnb[layer * NH + t];
    for (int l = 0; l < LTILE; l++) {
        float v = (glu[l][t] - mean_s[l]) * rstd_s[l] * lw + lb;
        hbuf[hbase + (size_t)l * NH + t] = v;
    }
}

// ---------------- fused head: gather + 3 MLP layers, one block per batch ----------------
__global__ void __launch_bounds__(256, 2)
s4w_head(const float* __restrict__ hbuf,
         const float* __restrict__ w1, const float* __restrict__ b1,
         const float* __restrict__ w2, const float* __restrict__ b2,
         const float* __restrict__ w3, const float* __restrict__ b3,
         float* __restrict__ out) {
    int b = blockIdx.x, t = threadIdx.x;
    __shared__ float h0[NH], a1[ML1], a2[ML2];
    h0[t] = hbuf[((size_t)b * LSEQ + (LSEQ - 1)) * NH + t];
    __syncthreads();
    for (int o = t; o < ML1; o += 256) {
        const float* wp = w1 + (size_t)o * NH;
        float acc = b1[o];
#pragma unroll 4
        for (int k = 0; k < NH; k++) acc = fmaf(wp[k], h0[k], acc);
        a1[o] = fmaxf(acc, 0.f);
    }
    __syncthreads();
    for (int o = t; o < ML2; o += 256) {
        const float* wp = w2 + (size_t)o * ML1;
        float acc = b2[o];
#pragma unroll 4
        for (int k = 0; k < ML1; k++) acc = fmaf(wp[k], a1[k], acc);
        a2[o] = fmaxf(acc, 0.f);
    }
    __syncthreads();
    for (int o = t; o < MOUT; o += 256) {
        const float* wp = w3 + (size_t)o * ML2;
        float acc = b3[o];
#pragma unroll 4
        for (int k = 0; k < ML2; k++) acc = fmaf(wp[k], a2[k], acc);
        out[(size_t)b * MOUT + o] = acc;
    }
}

extern "C" void kernel_launch(void* const* d_in, const int* in_sizes, int n_in,
                              void* d_out, int out_size, void* d_ws, size_t ws_size,
                              hipStream_t stream) {
    const float* x          = (const float*)d_in[0];
    const float* enc_w      = (const float*)d_in[1];
    const float* enc_b      = (const float*)d_in[2];
    const float* log_dt     = (const float*)d_in[3];
    const float* C_re       = (const float*)d_in[4];
    const float* C_im       = (const float*)d_in[5];
    const float* log_A_real = (const float*)d_in[6];
    const float* A_imag     = (const float*)d_in[7];
    const float* Dp         = (const float*)d_in[8];
    const float* out_w      = (const float*)d_in[9];
    const float* out_b      = (const float*)d_in[10];
    const float* ln_w       = (const float*)d_in[11];
    const float* ln_b       = (const float*)d_in[12];
    const float* lin1_w     = (const float*)d_in[13];
    const float* lin1_b     = (const float*)d_in[14];
    const float* lin2_w     = (const float*)d_in[15];
    const float* lin2_b     = (const float*)d_in[16];
    const float* lin3_w     = (const float*)d_in[17];
    const float* lin3_b     = (const float*)d_in[18];
    float* outp = (float*)d_out;

    float* ws = (float*)d_ws;
    size_t off = 0;
    float* hbuf   = ws + off; off += (size_t)NB * LSEQ * NH;
    __hip_bfloat16* ybf = (__hip_bfloat16*)(ws + off); off += (size_t)NB * LSEQ * NH / 2;
    __hip_bfloat16* wbf = (__hip_bfloat16*)(ws + off); off += (size_t)NLAY * 2 * NH * NH / 2;
    float2* states = (float2*)(ws + off); off += (size_t)NB * NCH * NH * NN * 2;
    float* ctr    = ws + off; off += NLAY * NH * NN;
    float* cti    = ws + off; off += NLAY * NH * NN;
    float* er_    = ws + off; off += NLAY * NH * NN;
    float* ei_    = ws + off; off += NLAY * NH * NN;
    float* pr_    = ws + off; off += NLAY * NH * NN;
    float* pi_    = ws + off; off += NLAY * NH * NN;

    s4w_coef<<<(NLAY * NH * NN + 255) / 256, 256, 0, stream>>>(
        log_dt, C_re, C_im, log_A_real, A_imag, ctr, cti, er_, ei_, pr_, pi_);

    s4w_wprep<<<(NLAY * 2 * NH * NH) / 256, 256, 0, stream>>>(out_w, wbf);

    s4w_enc<<<NB * (LSEQ / 16), 256, 0, stream>>>(x, enc_w, enc_b, hbuf);

    for (int layer = 0; layer < NLAY; layer++) {
        s4w_convA<<<dim3(NB, NCH), 256, 0, stream>>>(hbuf, er_, ei_, states, layer);
        s4w_scan<<<(NB * NH * NN) / 256, 256, 0, stream>>>(states, pr_, pi_, layer);
        s4w_convC<<<dim3(NB, NCH), 256, 0, stream>>>(hbuf, ybf, states, er_, ei_, ctr, cti, Dp, layer);
        s4w_proj_mfma<<<dim3(NB, LSEQ / LTILE), 256, 0, stream>>>(ybf, hbuf, wbf, out_b, ln_w, ln_b, layer);
    }

    s4w_head<<<NB, 256, 0, stream>>>(hbuf, lin1_w, lin1_b, lin2_w, lin2_b, lin3_w, lin3_b, outp);
}

// Round 6
// 657.975 us; speedup vs baseline: 1.1924x; 1.1924x over previous
//
#include <hip/hip_runtime.h>
#include <hip/hip_bf16.h>
#include <math.h>

#define NB 32
#define LSEQ 2048
#define DIN 64
#define NH 256
#define NN 32
#define NLAY 2
#define NCH 32
#define TCH 64    // LSEQ/NCH
#define LTILE 64
#define ML1 350
#define ML2 400
#define MOUT 1024
#define LN_EPS 1e-5f

typedef short short8 __attribute__((ext_vector_type(8)));
typedef float f32x4 __attribute__((ext_vector_type(4)));
typedef float f32x2 __attribute__((ext_vector_type(2)));

// Complex recurrence via packed f32 (VOP3P), 2 instructions per state-step:
//   R = pk_fma(E, S, U)  with E lo-broadcast, U=(u,0):
//       R.lo = er*sr + u ; R.hi = er*si
//   S = pk_fma(E, S, R)  with E hi for both halves, S swapped, neg_lo on E:
//       S.lo = -ei*si + R.lo = er*sr - ei*si + u
//       S.hi =  ei*sr + R.hi = ei*sr + er*si
#define PK_STEP(E, S, U)                                                        \
    {                                                                           \
        f32x2 R_;                                                               \
        asm("v_pk_fma_f32 %0, %1, %2, %3 op_sel:[0,0,0] op_sel_hi:[0,1,1]"      \
            : "=v"(R_) : "v"(E), "v"(S), "v"(U));                               \
        asm("v_pk_fma_f32 %0, %1, %0, %2 op_sel:[1,1,0] op_sel_hi:[1,0,1] neg_lo:[1,0,0]" \
            : "+v"(S) : "v"(E), "v"(R_));                                       \
    }
// A += (cr*nsr, -ci*nsi):
#define PK_ACC(C, S, A)                                                         \
    asm("v_pk_fma_f32 %0, %1, %2, %0 neg_hi:[1,0,0]" : "+v"(A) : "v"(C), "v"(S));

// ---------------- coefficient prep ----------------
__global__ void s4w_coef(const float* __restrict__ log_dt,
                         const float* __restrict__ C_re, const float* __restrict__ C_im,
                         const float* __restrict__ log_A_real, const float* __restrict__ A_imag,
                         float* __restrict__ ctr, float* __restrict__ cti,
                         float* __restrict__ er_, float* __restrict__ ei_,
                         float* __restrict__ pr_, float* __restrict__ pi_) {
    int idx = blockIdx.x * 256 + threadIdx.x;
    if (idx >= NLAY * NH * NN) return;
    int h = (idx / NN) % NH;
    int l = idx / (NN * NH);
    float dt = expf(log_dt[l * NH + h]);
    float ar = -expf(log_A_real[idx]);
    float ai = A_imag[idx];
    float dre = ar * dt, dim = ai * dt;
    float ex = expf(dre);
    float er = ex * cosf(dim);
    float ei = ex * sinf(dim);
    float den = ar * ar + ai * ai;
    float qr = ((er - 1.0f) * ar + ei * ai) / den;
    float qi = (ei * ar - (er - 1.0f) * ai) / den;
    float cr = C_re[idx], ci = C_im[idx];
    ctr[idx] = 2.0f * (cr * qr - ci * qi);
    cti[idx] = 2.0f * (cr * qi + ci * qr);
    er_[idx] = er; ei_[idx] = ei;
    double exT = exp((double)dre * (double)TCH);
    double ang = (double)dim * (double)TCH;
    pr_[idx] = (float)(exT * cos(ang));
    pi_[idx] = (float)(exT * sin(ang));
}

// ---------------- weight prep: out_w -> bf16 ----------------
__global__ void s4w_wprep(const float* __restrict__ ow, __hip_bfloat16* __restrict__ wbf) {
    int idx = blockIdx.x * 256 + threadIdx.x;
    wbf[idx] = __float2bfloat16(ow[idx]);
}

// ---------------- encoder ----------------
__global__ void __launch_bounds__(256, 2)
s4w_enc(const float* __restrict__ x, const float* __restrict__ w,
        const float* __restrict__ bias, float* __restrict__ hbuf) {
    int blk = blockIdx.x;
    int b = blk / (LSEQ / 16);
    int l0 = (blk % (LSEQ / 16)) * 16;
    int t = threadIdx.x;
    __shared__ float xs[16][DIN];
    ((float4*)&xs[0][0])[t] = ((const float4*)(x + ((size_t)b * LSEQ + l0) * DIN))[t];
    float wr[DIN];
    const float4* wp4 = (const float4*)(w + (size_t)t * DIN);
#pragma unroll
    for (int i = 0; i < DIN / 4; i++) {
        float4 v = wp4[i];
        wr[4 * i] = v.x; wr[4 * i + 1] = v.y; wr[4 * i + 2] = v.z; wr[4 * i + 3] = v.w;
    }
    float bz = bias[t];
    __syncthreads();
#pragma unroll 4
    for (int l = 0; l < 16; l++) {
        float acc = bz;
#pragma unroll
        for (int i = 0; i < DIN; i++) acc = fmaf(wr[i], xs[l][i], acc);
        hbuf[((size_t)b * LSEQ + l0 + l) * NH + t] = acc;
    }
}

// ---------------- conv phase A (packed f32) ----------------
__global__ void __launch_bounds__(256, 1)
s4w_convA(const float* __restrict__ hbuf,
          const float* __restrict__ er_, const float* __restrict__ ei_,
          float2* __restrict__ states, int layer) {
    int b = blockIdx.x, c = blockIdx.y, h = threadIdx.x;
    f32x2 E[NN], S[NN];
    const float* eb0 = er_ + (size_t)(layer * NH + h) * NN;
    const float* eb1 = ei_ + (size_t)(layer * NH + h) * NN;
#pragma unroll
    for (int n = 0; n < NN; n++) {
        E[n].x = eb0[n]; E[n].y = eb1[n];
        S[n].x = 0.f; S[n].y = 0.f;
    }
    const float* up = hbuf + ((size_t)b * LSEQ + c * TCH) * NH + h;
#pragma unroll 2
    for (int j = 0; j < TCH; j++) {
        f32x2 U;
        U.x = up[(size_t)j * NH];
        U.y = 0.f;
#pragma unroll
        for (int n = 0; n < NN; n++) PK_STEP(E[n], S[n], U)
    }
    float2* sp = states + ((size_t)(b * NCH + c) * NH + h) * NN;
#pragma unroll
    for (int n = 0; n < NN; n++) sp[n] = make_float2(S[n].x, S[n].y);
}

// ---------------- conv phase B: inter-chunk scan ----------------
__global__ void s4w_scan(float2* __restrict__ states,
                         const float* __restrict__ pr_, const float* __restrict__ pi_, int layer) {
    int idx = blockIdx.x * 256 + threadIdx.x;
    int b = idx / (NH * NN);
    int hn = idx % (NH * NN);
    float pr = pr_[(size_t)layer * NH * NN + hn];
    float pi = pi_[(size_t)layer * NH * NN + hn];
    float sr = 0.f, si = 0.f;
    float2* sp = states + (size_t)b * NCH * NH * NN + hn;
    for (int c = 0; c < NCH; c++) {
        float2 e = sp[(size_t)c * NH * NN];
        sp[(size_t)c * NH * NN] = make_float2(sr, si);
        float nsr = pr * sr - pi * si + e.x;
        float nsi = pr * si + pi * sr + e.y;
        sr = nsr; si = nsi;
    }
}

// ---------------- conv phase C (packed f32): replay + Dp + GELU -> bf16 ----------------
__global__ void __launch_bounds__(256, 1)
s4w_convC(const float* __restrict__ hbuf, __hip_bfloat16* __restrict__ ybf,
          const float2* __restrict__ states,
          const float* __restrict__ er_, const float* __restrict__ ei_,
          const float* __restrict__ ctr_, const float* __restrict__ cti_,
          const float* __restrict__ Dp, int layer) {
    int b = blockIdx.x, c = blockIdx.y, h = threadIdx.x;
    f32x2 E[NN], S[NN], C[NN];
    size_t cbase = (size_t)(layer * NH + h) * NN;
    const float2* sp = states + ((size_t)(b * NCH + c) * NH + h) * NN;
#pragma unroll
    for (int n = 0; n < NN; n++) {
        E[n].x = er_[cbase + n]; E[n].y = ei_[cbase + n];
        C[n].x = ctr_[cbase + n]; C[n].y = cti_[cbase + n];
        float2 s0 = sp[n];
        S[n].x = s0.x; S[n].y = s0.y;
    }
    float dp = Dp[layer * NH + h];
    const float* up = hbuf + ((size_t)b * LSEQ + c * TCH) * NH + h;
    __hip_bfloat16* yp = ybf + ((size_t)b * LSEQ + c * TCH) * NH + h;
#pragma unroll 2
    for (int j = 0; j < TCH; j++) {
        float u = up[(size_t)j * NH];
        f32x2 U; U.x = u; U.y = 0.f;
        f32x2 A0; A0.x = 0.f; A0.y = 0.f;
        f32x2 A1; A1.x = 0.f; A1.y = 0.f;
#pragma unroll
        for (int n = 0; n < NN; n++) {
            PK_STEP(E[n], S[n], U)
            if (n & 1) { PK_ACC(C[n], S[n], A1) }
            else       { PK_ACC(C[n], S[n], A0) }
        }
        float yv = (A0.x + A0.y) + (A1.x + A1.y);
        yv = fmaf(u, dp, yv);
        float g = 0.5f * yv * (1.0f + erff(yv * 0.70710678118f));
        yp[(size_t)j * NH] = __float2bfloat16(g);
    }
}

// ---------------- proj: bf16 MFMA GEMM + GLU + residual + channel-LN ----------------
__global__ void __launch_bounds__(256, 2)
s4w_proj_mfma(const __hip_bfloat16* __restrict__ ybf, float* __restrict__ hbuf,
              const __hip_bfloat16* __restrict__ wbf, const float* __restrict__ ob,
              const float* __restrict__ lnw, const float* __restrict__ lnb, int layer) {
    int b = blockIdx.x;
    int n0 = blockIdx.y * LTILE;
    int t = threadIdx.x;
    int wave = t >> 6, lane = t & 63;
    int lm = lane & 15, kg = lane >> 4;

    __shared__ float glu[LTILE][NH + 1];
    __shared__ float ps[256], pq[256];
    __shared__ float mean_s[LTILE], rstd_s[LTILE];

    f32x4 acc[8][4];
#pragma unroll
    for (int i = 0; i < 8; i++)
#pragma unroll
        for (int j = 0; j < 4; j++) acc[i][j] = (f32x4){0.f, 0.f, 0.f, 0.f};

    const short* wp = (const short*)(wbf) + (size_t)layer * 512 * NH;
    const short* yp = (const short*)(ybf) + ((size_t)b * LSEQ + n0) * NH;

    const short8* aptr[8];
#pragma unroll
    for (int mi = 0; mi < 8; mi++) {
        int o = (mi < 4 ? wave * 64 + mi * 16 : 256 + wave * 64 + (mi - 4) * 16) + lm;
        aptr[mi] = (const short8*)(wp + (size_t)o * NH + kg * 8);
    }
    const short8* bptr[4];
#pragma unroll
    for (int ni = 0; ni < 4; ni++) {
        int l = ni * 16 + lm;
        bptr[ni] = (const short8*)(yp + (size_t)l * NH + kg * 8);
    }

#pragma unroll
    for (int ks = 0; ks < 8; ks++) {
        short8 bv[4], av[8];
#pragma unroll
        for (int ni = 0; ni < 4; ni++) bv[ni] = bptr[ni][ks * 4];
#pragma unroll
        for (int mi = 0; mi < 8; mi++) av[mi] = aptr[mi][ks * 4];
#pragma unroll
        for (int mi = 0; mi < 8; mi++)
#pragma unroll
            for (int ni = 0; ni < 4; ni++)
                acc[mi][ni] = __builtin_amdgcn_mfma_f32_16x16x32_bf16(av[mi], bv[ni], acc[mi][ni], 0, 0, 0);
    }

    float oba[4][4], obg[4][4];
#pragma unroll
    for (int mi = 0; mi < 4; mi++)
#pragma unroll
        for (int j = 0; j < 4; j++) {
            int o = wave * 64 + mi * 16 + kg * 4 + j;
            oba[mi][j] = ob[layer * 2 * NH + o];
            obg[mi][j] = ob[layer * 2 * NH + NH + o];
        }
#pragma unroll
    for (int mi = 0; mi < 4; mi++)
#pragma unroll
        for (int ni = 0; ni < 4; ni++)
#pragma unroll
            for (int j = 0; j < 4; j++) {
                float a = acc[mi][ni][j] + oba[mi][j];
                float g = acc[mi + 4][ni][j] + obg[mi][j];
                float v = a * (1.0f / (1.0f + expf(-g)));
                int o = wave * 64 + mi * 16 + kg * 4 + j;
                int l = ni * 16 + lm;
                glu[l][o] = v;
            }
    __syncthreads();

    const size_t hbase = ((size_t)b * LSEQ + n0) * NH;
    for (int l = 0; l < LTILE; l++)
        glu[l][t] += hbuf[hbase + (size_t)l * NH + t];
    __syncthreads();

    {
        int l = t & 63, seg = t >> 6;
        float s = 0.f, q = 0.f;
#pragma unroll
        for (int i = 0; i < 64; i++) {
            float v = glu[l][seg * 64 + i];
            s += v; q = fmaf(v, v, q);
        }
        ps[t] = s; pq[t] = q;
    }
    __syncthreads();
    if (t < 64) {
        float S = ps[t] + ps[64 + t] + ps[128 + t] + ps[192 + t];
        float Q = pq[t] + pq[64 + t] + pq[128 + t] + pq[192 + t];
        float m = S * (1.0f / NH);
        float v = Q * (1.0f / NH) - m * m;
        mean_s[t] = m; rstd_s[t] = rsqrtf(v + LN_EPS);
    }
    __syncthreads();

    float lw = lnw[layer * NH + t], lb = lnb[layer * NH + t];
    for (int l = 0; l < LTILE; l++) {
        float v = (glu[l][t] - mean_s[l]) * rstd_s[l] * lw + lb;
        hbuf[hbase + (size_t)l * NH + t] = v;
    }
}

// ---------------- head MLP: one wave per output element, lane-split K ----------------
__global__ void __launch_bounds__(256, 4)
s4w_mlp_wave(const float* __restrict__ in, size_t in_bstride,
             const float* __restrict__ w, const float* __restrict__ bias,
             float* __restrict__ out, int K, int N, int do_relu) {
    int wid = (blockIdx.x * 256 + threadIdx.x) >> 6;
    int lane = threadIdx.x & 63;
    if (wid >= NB * N) return;
    int b = wid / N, o = wid % N;
    const float* ip = in + (size_t)b * in_bstride;
    const float* wp = w + (size_t)o * K;
    float acc = 0.f;
    for (int k = lane; k < K; k += 64) acc = fmaf(wp[k], ip[k], acc);
#pragma unroll
    for (int off = 32; off > 0; off >>= 1) acc += __shfl_xor(acc, off, 64);
    if (lane == 0) {
        float v = acc + bias[o];
        out[(size_t)b * N + o] = do_relu ? fmaxf(v, 0.f) : v;
    }
}

extern "C" void kernel_launch(void* const* d_in, const int* in_sizes, int n_in,
                              void* d_out, int out_size, void* d_ws, size_t ws_size,
                              hipStream_t stream) {
    const float* x          = (const float*)d_in[0];
    const float* enc_w      = (const float*)d_in[1];
    const float* enc_b      = (const float*)d_in[2];
    const float* log_dt     = (const float*)d_in[3];
    const float* C_re       = (const float*)d_in[4];
    const float* C_im       = (const float*)d_in[5];
    const float* log_A_real = (const float*)d_in[6];
    const float* A_imag     = (const float*)d_in[7];
    const float* Dp         = (const float*)d_in[8];
    const float* out_w      = (const float*)d_in[9];
    const float* out_b      = (const float*)d_in[10];
    const float* ln_w       = (const float*)d_in[11];
    const float* ln_b       = (const float*)d_in[12];
    const float* lin1_w     = (const float*)d_in[13];
    const float* lin1_b     = (const float*)d_in[14];
    const float* lin2_w     = (const float*)d_in[15];
    const float* lin2_b     = (const float*)d_in[16];
    const float* lin3_w     = (const float*)d_in[17];
    const float* lin3_b     = (const float*)d_in[18];
    float* outp = (float*)d_out;

    float* ws = (float*)d_ws;
    size_t off = 0;
    float* hbuf   = ws + off; off += (size_t)NB * LSEQ * NH;
    __hip_bfloat16* ybf = (__hip_bfloat16*)(ws + off); off += (size_t)NB * LSEQ * NH / 2;
    __hip_bfloat16* wbf = (__hip_bfloat16*)(ws + off); off += (size_t)NLAY * 2 * NH * NH / 2;
    float2* states = (float2*)(ws + off); off += (size_t)NB * NCH * NH * NN * 2;
    float* ctr    = ws + off; off += NLAY * NH * NN;
    float* cti    = ws + off; off += NLAY * NH * NN;
    float* er_    = ws + off; off += NLAY * NH * NN;
    float* ei_    = ws + off; off += NLAY * NH * NN;
    float* pr_    = ws + off; off += NLAY * NH * NN;
    float* pi_    = ws + off; off += NLAY * NH * NN;
    float* t1     = ws + off; off += NB * ML1;
    float* t2     = ws + off; off += NB * ML2;

    s4w_coef<<<(NLAY * NH * NN + 255) / 256, 256, 0, stream>>>(
        log_dt, C_re, C_im, log_A_real, A_imag, ctr, cti, er_, ei_, pr_, pi_);

    s4w_wprep<<<(NLAY * 2 * NH * NH) / 256, 256, 0, stream>>>(out_w, wbf);

    s4w_enc<<<NB * (LSEQ / 16), 256, 0, stream>>>(x, enc_w, enc_b, hbuf);

    for (int layer = 0; layer < NLAY; layer++) {
        s4w_convA<<<dim3(NB, NCH), 256, 0, stream>>>(hbuf, er_, ei_, states, layer);
        s4w_scan<<<(NB * NH * NN) / 256, 256, 0, stream>>>(states, pr_, pi_, layer);
        s4w_convC<<<dim3(NB, NCH), 256, 0, stream>>>(hbuf, ybf, states, er_, ei_, ctr, cti, Dp, layer);
        s4w_proj_mfma<<<dim3(NB, LSEQ / LTILE), 256, 0, stream>>>(ybf, hbuf, wbf, out_b, ln_w, ln_b, layer);
    }

    s4w_mlp_wave<<<(NB * ML1 + 3) / 4, 256, 0, stream>>>(
        hbuf + (size_t)(LSEQ - 1) * NH, (size_t)LSEQ * NH, lin1_w, lin1_b, t1, NH, ML1, 1);
    s4w_mlp_wave<<<(NB * ML2 + 3) / 4, 256, 0, stream>>>(
        t1, ML1, lin2_w, lin2_b, t2, ML1, ML2, 1);
    s4w_mlp_wave<<<(NB * MOUT + 3) / 4, 256, 0, stream>>>(
        t2, ML2, lin3_w, lin3_b, outp, ML2, MOUT, 0);
}

// Round 7
// 657.518 us; speedup vs baseline: 1.1932x; 1.0007x over previous
//
#include <hip/hip_runtime.h>
#include <hip/hip_bf16.h>
#include <math.h>

#define NB 32
#define LSEQ 2048
#define DIN 64
#define NH 256
#define NN 32
#define NST 16    // states per thread (lane-pair split)
#define NLAY 2
#define NCH 32
#define TCH 64    // LSEQ/NCH
#define LTILE 64
#define ML1 350
#define ML2 400
#define MOUT 1024
#define LN_EPS 1e-5f

typedef short short8 __attribute__((ext_vector_type(8)));
typedef float f32x4 __attribute__((ext_vector_type(4)));
typedef float f32x2 __attribute__((ext_vector_type(2)));

// Complex recurrence via packed f32 (VOP3P), 2 instructions per state-step:
//   R = pk_fma(E, S, U)  with E lo-broadcast, U=(u,0):
//       R.lo = er*sr + u ; R.hi = er*si
//   S = pk_fma(E, S, R)  with E hi for both halves, S swapped, neg_lo on E:
//       S.lo = -ei*si + R.lo = er*sr - ei*si + u
//       S.hi =  ei*sr + R.hi = ei*sr + er*si
#define PK_STEP(E, S, U)                                                        \
    {                                                                           \
        f32x2 R_;                                                               \
        asm("v_pk_fma_f32 %0, %1, %2, %3 op_sel:[0,0,0] op_sel_hi:[0,1,1]"      \
            : "=v"(R_) : "v"(E), "v"(S), "v"(U));                               \
        asm("v_pk_fma_f32 %0, %1, %0, %2 op_sel:[1,1,0] op_sel_hi:[1,0,1] neg_lo:[1,0,0]" \
            : "+v"(S) : "v"(E), "v"(R_));                                       \
    }
// A += (cr*sr, -ci*si):
#define PK_ACC(C, S, A)                                                         \
    asm("v_pk_fma_f32 %0, %1, %2, %0 neg_hi:[1,0,0]" : "+v"(A) : "v"(C), "v"(S));

// ---------------- coefficient prep ----------------
__global__ void s4w_coef(const float* __restrict__ log_dt,
                         const float* __restrict__ C_re, const float* __restrict__ C_im,
                         const float* __restrict__ log_A_real, const float* __restrict__ A_imag,
                         float* __restrict__ ctr, float* __restrict__ cti,
                         float* __restrict__ er_, float* __restrict__ ei_,
                         float* __restrict__ pr_, float* __restrict__ pi_) {
    int idx = blockIdx.x * 256 + threadIdx.x;
    if (idx >= NLAY * NH * NN) return;
    int h = (idx / NN) % NH;
    int l = idx / (NN * NH);
    float dt = expf(log_dt[l * NH + h]);
    float ar = -expf(log_A_real[idx]);
    float ai = A_imag[idx];
    float dre = ar * dt, dim = ai * dt;
    float ex = expf(dre);
    float er = ex * cosf(dim);
    float ei = ex * sinf(dim);
    float den = ar * ar + ai * ai;
    float qr = ((er - 1.0f) * ar + ei * ai) / den;
    float qi = (ei * ar - (er - 1.0f) * ai) / den;
    float cr = C_re[idx], ci = C_im[idx];
    ctr[idx] = 2.0f * (cr * qr - ci * qi);
    cti[idx] = 2.0f * (cr * qi + ci * qr);
    er_[idx] = er; ei_[idx] = ei;
    double exT = exp((double)dre * (double)TCH);
    double ang = (double)dim * (double)TCH;
    pr_[idx] = (float)(exT * cos(ang));
    pi_[idx] = (float)(exT * sin(ang));
}

// ---------------- weight prep: out_w -> bf16 ----------------
__global__ void s4w_wprep(const float* __restrict__ ow, __hip_bfloat16* __restrict__ wbf) {
    int idx = blockIdx.x * 256 + threadIdx.x;
    wbf[idx] = __float2bfloat16(ow[idx]);
}

// ---------------- encoder ----------------
__global__ void __launch_bounds__(256, 2)
s4w_enc(const float* __restrict__ x, const float* __restrict__ w,
        const float* __restrict__ bias, float* __restrict__ hbuf) {
    int blk = blockIdx.x;
    int b = blk / (LSEQ / 16);
    int l0 = (blk % (LSEQ / 16)) * 16;
    int t = threadIdx.x;
    __shared__ float xs[16][DIN];
    ((float4*)&xs[0][0])[t] = ((const float4*)(x + ((size_t)b * LSEQ + l0) * DIN))[t];
    float wr[DIN];
    const float4* wp4 = (const float4*)(w + (size_t)t * DIN);
#pragma unroll
    for (int i = 0; i < DIN / 4; i++) {
        float4 v = wp4[i];
        wr[4 * i] = v.x; wr[4 * i + 1] = v.y; wr[4 * i + 2] = v.z; wr[4 * i + 3] = v.w;
    }
    float bz = bias[t];
    __syncthreads();
#pragma unroll 4
    for (int l = 0; l < 16; l++) {
        float acc = bz;
#pragma unroll
        for (int i = 0; i < DIN; i++) acc = fmaf(wr[i], xs[l][i], acc);
        hbuf[((size_t)b * LSEQ + l0 + l) * NH + t] = acc;
    }
}

// ---------------- conv phase A (packed f32, lane-pair split: 16 states/thread) ----------------
__global__ void __launch_bounds__(512, 2)
s4w_convA(const float* __restrict__ hbuf,
          const float* __restrict__ er_, const float* __restrict__ ei_,
          float2* __restrict__ states, int layer) {
    int b = blockIdx.x, c = blockIdx.y;
    int t = threadIdx.x;
    int h = t >> 1, half = t & 1;
    f32x2 E[NST], S[NST];
    const float* eb0 = er_ + (size_t)(layer * NH + h) * NN + half * NST;
    const float* eb1 = ei_ + (size_t)(layer * NH + h) * NN + half * NST;
#pragma unroll
    for (int n = 0; n < NST; n++) {
        E[n].x = eb0[n]; E[n].y = eb1[n];
        S[n].x = 0.f; S[n].y = 0.f;
    }
    const float* up = hbuf + ((size_t)b * LSEQ + c * TCH) * NH + h;
#pragma unroll 2
    for (int j = 0; j < TCH; j++) {
        f32x2 U;
        U.x = up[(size_t)j * NH];
        U.y = 0.f;
#pragma unroll
        for (int n = 0; n < NST; n++) PK_STEP(E[n], S[n], U)
    }
    float2* sp = states + ((size_t)(b * NCH + c) * NH + h) * NN + half * NST;
#pragma unroll
    for (int n = 0; n < NST; n++) sp[n] = make_float2(S[n].x, S[n].y);
}

// ---------------- conv phase B: inter-chunk scan ----------------
__global__ void s4w_scan(float2* __restrict__ states,
                         const float* __restrict__ pr_, const float* __restrict__ pi_, int layer) {
    int idx = blockIdx.x * 256 + threadIdx.x;
    int b = idx / (NH * NN);
    int hn = idx % (NH * NN);
    float pr = pr_[(size_t)layer * NH * NN + hn];
    float pi = pi_[(size_t)layer * NH * NN + hn];
    float sr = 0.f, si = 0.f;
    float2* sp = states + (size_t)b * NCH * NH * NN + hn;
    for (int c = 0; c < NCH; c++) {
        float2 e = sp[(size_t)c * NH * NN];
        sp[(size_t)c * NH * NN] = make_float2(sr, si);
        float nsr = pr * sr - pi * si + e.x;
        float nsi = pr * si + pi * sr + e.y;
        sr = nsr; si = nsi;
    }
}

// ---------------- conv phase C (packed f32, lane-pair split): replay + Dp + GELU -> bf16 ----------------
__global__ void __launch_bounds__(512, 2)
s4w_convC(const float* __restrict__ hbuf, __hip_bfloat16* __restrict__ ybf,
          const float2* __restrict__ states,
          const float* __restrict__ er_, const float* __restrict__ ei_,
          const float* __restrict__ ctr_, const float* __restrict__ cti_,
          const float* __restrict__ Dp, int layer) {
    int b = blockIdx.x, c = blockIdx.y;
    int t = threadIdx.x;
    int h = t >> 1, half = t & 1;
    f32x2 E[NST], S[NST], C[NST];
    size_t cbase = (size_t)(layer * NH + h) * NN + half * NST;
    const float2* sp = states + ((size_t)(b * NCH + c) * NH + h) * NN + half * NST;
#pragma unroll
    for (int n = 0; n < NST; n++) {
        E[n].x = er_[cbase + n]; E[n].y = ei_[cbase + n];
        C[n].x = ctr_[cbase + n]; C[n].y = cti_[cbase + n];
        float2 s0 = sp[n];
        S[n].x = s0.x; S[n].y = s0.y;
    }
    float dp = Dp[layer * NH + h];
    const float* up = hbuf + ((size_t)b * LSEQ + c * TCH) * NH + h;
    __hip_bfloat16* yp = ybf + ((size_t)b * LSEQ + c * TCH) * NH + h;
#pragma unroll 2
    for (int j = 0; j < TCH; j++) {
        float u = up[(size_t)j * NH];
        f32x2 U; U.x = u; U.y = 0.f;
        f32x2 A0; A0.x = 0.f; A0.y = 0.f;
        f32x2 A1; A1.x = 0.f; A1.y = 0.f;
#pragma unroll
        for (int n = 0; n < NST; n++) {
            PK_STEP(E[n], S[n], U)
            if (n & 1) { PK_ACC(C[n], S[n], A1) }
            else       { PK_ACC(C[n], S[n], A0) }
        }
        float part = (A0.x + A0.y) + (A1.x + A1.y);
        part += __shfl_xor(part, 1, 64);   // combine partner's 16 states
        float yv = fmaf(u, dp, part);
        float g = 0.5f * yv * (1.0f + erff(yv * 0.70710678118f));
        if (half == 0) yp[(size_t)j * NH] = __float2bfloat16(g);
    }
}

// ---------------- proj: bf16 MFMA GEMM + GLU + residual + channel-LN ----------------
__global__ void __launch_bounds__(256, 2)
s4w_proj_mfma(const __hip_bfloat16* __restrict__ ybf, float* __restrict__ hbuf,
              const __hip_bfloat16* __restrict__ wbf, const float* __restrict__ ob,
              const float* __restrict__ lnw, const float* __restrict__ lnb, int layer) {
    int b = blockIdx.x;
    int n0 = blockIdx.y * LTILE;
    int t = threadIdx.x;
    int wave = t >> 6, lane = t & 63;
    int lm = lane & 15, kg = lane >> 4;

    __shared__ float glu[LTILE][NH + 1];
    __shared__ float ps[256], pq[256];
    __shared__ float mean_s[LTILE], rstd_s[LTILE];

    f32x4 acc[8][4];
#pragma unroll
    for (int i = 0; i < 8; i++)
#pragma unroll
        for (int j = 0; j < 4; j++) acc[i][j] = (f32x4){0.f, 0.f, 0.f, 0.f};

    const short* wp = (const short*)(wbf) + (size_t)layer * 512 * NH;
    const short* yp = (const short*)(ybf) + ((size_t)b * LSEQ + n0) * NH;

    const short8* aptr[8];
#pragma unroll
    for (int mi = 0; mi < 8; mi++) {
        int o = (mi < 4 ? wave * 64 + mi * 16 : 256 + wave * 64 + (mi - 4) * 16) + lm;
        aptr[mi] = (const short8*)(wp + (size_t)o * NH + kg * 8);
    }
    const short8* bptr[4];
#pragma unroll
    for (int ni = 0; ni < 4; ni++) {
        int l = ni * 16 + lm;
        bptr[ni] = (const short8*)(yp + (size_t)l * NH + kg * 8);
    }

#pragma unroll
    for (int ks = 0; ks < 8; ks++) {
        short8 bv[4], av[8];
#pragma unroll
        for (int ni = 0; ni < 4; ni++) bv[ni] = bptr[ni][ks * 4];
#pragma unroll
        for (int mi = 0; mi < 8; mi++) av[mi] = aptr[mi][ks * 4];
#pragma unroll
        for (int mi = 0; mi < 8; mi++)
#pragma unroll
            for (int ni = 0; ni < 4; ni++)
                acc[mi][ni] = __builtin_amdgcn_mfma_f32_16x16x32_bf16(av[mi], bv[ni], acc[mi][ni], 0, 0, 0);
    }

    float oba[4][4], obg[4][4];
#pragma unroll
    for (int mi = 0; mi < 4; mi++)
#pragma unroll
        for (int j = 0; j < 4; j++) {
            int o = wave * 64 + mi * 16 + kg * 4 + j;
            oba[mi][j] = ob[layer * 2 * NH + o];
            obg[mi][j] = ob[layer * 2 * NH + NH + o];
        }
#pragma unroll
    for (int mi = 0; mi < 4; mi++)
#pragma unroll
        for (int ni = 0; ni < 4; ni++)
#pragma unroll
            for (int j = 0; j < 4; j++) {
                float a = acc[mi][ni][j] + oba[mi][j];
                float g = acc[mi + 4][ni][j] + obg[mi][j];
                float v = a * (1.0f / (1.0f + expf(-g)));
                int o = wave * 64 + mi * 16 + kg * 4 + j;
                int l = ni * 16 + lm;
                glu[l][o] = v;
            }
    __syncthreads();

    const size_t hbase = ((size_t)b * LSEQ + n0) * NH;
    for (int l = 0; l < LTILE; l++)
        glu[l][t] += hbuf[hbase + (size_t)l * NH + t];
    __syncthreads();

    {
        int l = t & 63, seg = t >> 6;
        float s = 0.f, q = 0.f;
#pragma unroll
        for (int i = 0; i < 64; i++) {
            float v = glu[l][seg * 64 + i];
            s += v; q = fmaf(v, v, q);
        }
        ps[t] = s; pq[t] = q;
    }
    __syncthreads();
    if (t < 64) {
        float S = ps[t] + ps[64 + t] + ps[128 + t] + ps[192 + t];
        float Q = pq[t] + pq[64 + t] + pq[128 + t] + pq[192 + t];
        float m = S * (1.0f / NH);
        float v = Q * (1.0f / NH) - m * m;
        mean_s[t] = m; rstd_s[t] = rsqrtf(v + LN_EPS);
    }
    __syncthreads();

    float lw = lnw[layer * NH + t], lb = lnb[layer * NH + t];
    for (int l = 0; l < LTILE; l++) {
        float v = (glu[l][t] - mean_s[l]) * rstd_s[l] * lw + lb;
        hbuf[hbase + (size_t)l * NH + t] = v;
    }
}

// ---------------- head MLP: one wave per output element, lane-split K ----------------
__global__ void __launch_bounds__(256, 4)
s4w_mlp_wave(const float* __restrict__ in, size_t in_bstride,
             const float* __restrict__ w, const float* __restrict__ bias,
             float* __restrict__ out, int K, int N, int do_relu) {
    int wid = (blockIdx.x * 256 + threadIdx.x) >> 6;
    int lane = threadIdx.x & 63;
    if (wid >= NB * N) return;
    int b = wid / N, o = wid % N;
    const float* ip = in + (size_t)b * in_bstride;
    const float* wp = w + (size_t)o * K;
    float acc = 0.f;
    for (int k = lane; k < K; k += 64) acc = fmaf(wp[k], ip[k], acc);
#pragma unroll
    for (int off = 32; off > 0; off >>= 1) acc += __shfl_xor(acc, off, 64);
    if (lane == 0) {
        float v = acc + bias[o];
        out[(size_t)b * N + o] = do_relu ? fmaxf(v, 0.f) : v;
    }
}

extern "C" void kernel_launch(void* const* d_in, const int* in_sizes, int n_in,
                              void* d_out, int out_size, void* d_ws, size_t ws_size,
                              hipStream_t stream) {
    const float* x          = (const float*)d_in[0];
    const float* enc_w      = (const float*)d_in[1];
    const float* enc_b      = (const float*)d_in[2];
    const float* log_dt     = (const float*)d_in[3];
    const float* C_re       = (const float*)d_in[4];
    const float* C_im       = (const float*)d_in[5];
    const float* log_A_real = (const float*)d_in[6];
    const float* A_imag     = (const float*)d_in[7];
    const float* Dp         = (const float*)d_in[8];
    const float* out_w      = (const float*)d_in[9];
    const float* out_b      = (const float*)d_in[10];
    const float* ln_w       = (const float*)d_in[11];
    const float* ln_b       = (const float*)d_in[12];
    const float* lin1_w     = (const float*)d_in[13];
    const float* lin1_b     = (const float*)d_in[14];
    const float* lin2_w     = (const float*)d_in[15];
    const float* lin2_b     = (const float*)d_in[16];
    const float* lin3_w     = (const float*)d_in[17];
    const float* lin3_b     = (const float*)d_in[18];
    float* outp = (float*)d_out;

    float* ws = (float*)d_ws;
    size_t off = 0;
    float* hbuf   = ws + off; off += (size_t)NB * LSEQ * NH;
    __hip_bfloat16* ybf = (__hip_bfloat16*)(ws + off); off += (size_t)NB * LSEQ * NH / 2;
    __hip_bfloat16* wbf = (__hip_bfloat16*)(ws + off); off += (size_t)NLAY * 2 * NH * NH / 2;
    float2* states = (float2*)(ws + off); off += (size_t)NB * NCH * NH * NN * 2;
    float* ctr    = ws + off; off += NLAY * NH * NN;
    float* cti    = ws + off; off += NLAY * NH * NN;
    float* er_    = ws + off; off += NLAY * NH * NN;
    float* ei_    = ws + off; off += NLAY * NH * NN;
    float* pr_    = ws + off; off += NLAY * NH * NN;
    float* pi_    = ws + off; off += NLAY * NH * NN;
    float* t1     = ws + off; off += NB * ML1;
    float* t2     = ws + off; off += NB * ML2;

    s4w_coef<<<(NLAY * NH * NN + 255) / 256, 256, 0, stream>>>(
        log_dt, C_re, C_im, log_A_real, A_imag, ctr, cti, er_, ei_, pr_, pi_);

    s4w_wprep<<<(NLAY * 2 * NH * NH) / 256, 256, 0, stream>>>(out_w, wbf);

    s4w_enc<<<NB * (LSEQ / 16), 256, 0, stream>>>(x, enc_w, enc_b, hbuf);

    for (int layer = 0; layer < NLAY; layer++) {
        s4w_convA<<<dim3(NB, NCH), 512, 0, stream>>>(hbuf, er_, ei_, states, layer);
        s4w_scan<<<(NB * NH * NN) / 256, 256, 0, stream>>>(states, pr_, pi_, layer);
        s4w_convC<<<dim3(NB, NCH), 512, 0, stream>>>(hbuf, ybf, states, er_, ei_, ctr, cti, Dp, layer);
        s4w_proj_mfma<<<dim3(NB, LSEQ / LTILE), 256, 0, stream>>>(ybf, hbuf, wbf, out_b, ln_w, ln_b, layer);
    }

    s4w_mlp_wave<<<(NB * ML1 + 3) / 4, 256, 0, stream>>>(
        hbuf + (size_t)(LSEQ - 1) * NH, (size_t)LSEQ * NH, lin1_w, lin1_b, t1, NH, ML1, 1);
    s4w_mlp_wave<<<(NB * ML2 + 3) / 4, 256, 0, stream>>>(
        t1, ML1, lin2_w, lin2_b, t2, ML1, ML2, 1);
    s4w_mlp_wave<<<(NB * MOUT + 3) / 4, 256, 0, stream>>>(
        t2, ML2, lin3_w, lin3_b, outp, ML2, MOUT, 0);
}